// Round 2
// baseline (3032.534 us; speedup 1.0000x reference)
//
#include <hip/hip_runtime.h>
#include <hip/hip_bf16.h>
#include <cstdint>
#include <cstddef>

// Problem dims (fixed)
#define TSTEPS 128
#define BATCH  64
#define DDIM   1024
#define HDIM   1024
#define HADIM  128
#define VOCAB  10000
#define MROWS  (TSTEPS * BATCH)   // 8192

typedef __attribute__((ext_vector_type(8))) short bf16x8;
typedef __attribute__((ext_vector_type(4))) float f32x4;

__device__ __forceinline__ unsigned short f2bf(float x) {
    unsigned int u = __float_as_uint(x);
    unsigned int r = (u + 0x7fffu + ((u >> 16) & 1u)) >> 16;
    return (unsigned short)r;
}

// ---------------- transpose + cast fp32 -> bf16 (W: RxC -> Wt: CxR) ----------------
__global__ __launch_bounds__(256) void transpose_cast(const float* __restrict__ W,
                                                      unsigned short* __restrict__ Wt,
                                                      int R, int C) {
    __shared__ float tile[32][33];
    int tc = blockIdx.x * 32;   // col base in W
    int tr = blockIdx.y * 32;   // row base in W
    int tid = threadIdx.x;
    for (int i = 0; i < 4; i++) {
        int idx = tid + i * 256;
        int r = idx >> 5, c = idx & 31;
        float v = 0.f;
        if (tr + r < R && tc + c < C) v = W[(size_t)(tr + r) * C + tc + c];
        tile[r][c] = v;
    }
    __syncthreads();
    for (int i = 0; i < 4; i++) {
        int idx = tid + i * 256;
        int r = idx >> 5, c = idx & 31;   // r = row of Wt (= col of W)
        if (tc + r < C && tr + c < R)
            Wt[(size_t)(tc + r) * R + tr + c] = f2bf(tile[c][r]);
    }
}

// ---------------- gather embedding rows + cast to bf16 ----------------
__global__ __launch_bounds__(256) void gather_cast(const int* __restrict__ tok,
                                                   const float* __restrict__ emb,
                                                   unsigned short* __restrict__ xb) {
    int i = blockIdx.x;               // 0..8191 (t*64+b)
    int t = tok[i];
    const float4* src = (const float4*)(emb + (size_t)t * DDIM);
    float4 v = src[threadIdx.x];
    ushort4 o;
    o.x = f2bf(v.x); o.y = f2bf(v.y); o.z = f2bf(v.z); o.w = f2bf(v.w);
    ((ushort4*)(xb + (size_t)i * DDIM))[threadIdx.x] = o;
}

__global__ __launch_bounds__(256) void zero_u32(unsigned int* p, int n) {
    int i = blockIdx.x * 256 + threadIdx.x;
    if (i < n) p[i] = 0u;
}

// ---------------- C = A @ Bt^T + bias, 128x128 tile, bf16 in / fp32 out ----------------
// A: MxK bf16 row-major; Bt: NxK bf16 row-major; C: MxN fp32.
// K mult of 32, M mult of 128. grid = (M/128, ceil(N/128)), 256 threads.
__global__ __launch_bounds__(256) void gemm128(const unsigned short* __restrict__ A,
                                               const unsigned short* __restrict__ Bt,
                                               const float* __restrict__ bias,
                                               float* __restrict__ C,
                                               int M, int N, int K) {
    __shared__ unsigned short As[128 * 40];
    __shared__ unsigned short Bs[128 * 40];
    const int tid = threadIdx.x;
    const int wave = tid >> 6, lane = tid & 63;
    const int wr = wave >> 1, wc = wave & 1;
    const int quad = lane >> 4, lr = lane & 15;
    const int rowBase = blockIdx.x * 128;
    const int colBase = blockIdx.y * 128;
    const int sr = tid >> 2;            // 0..63
    const int sk = (tid & 3) * 8;       // 0,8,16,24
    const unsigned short* Ag0 = A + (size_t)(rowBase + sr) * K + sk;
    const unsigned short* Ag1 = Ag0 + (size_t)64 * K;
    int cb0 = colBase + sr;      if (cb0 > N - 1) cb0 = N - 1;
    int cb1 = colBase + 64 + sr; if (cb1 > N - 1) cb1 = N - 1;
    const unsigned short* Bg0 = Bt + (size_t)cb0 * K + sk;
    const unsigned short* Bg1 = Bt + (size_t)cb1 * K + sk;

    f32x4 acc[4][4] = {};
    uint4 a0 = *(const uint4*)Ag0, a1 = *(const uint4*)Ag1;
    uint4 b0 = *(const uint4*)Bg0, b1 = *(const uint4*)Bg1;
    for (int k0 = 0; k0 < K; k0 += 32) {
        __syncthreads();
        *(uint4*)&As[sr * 40 + sk] = a0;
        *(uint4*)&As[(64 + sr) * 40 + sk] = a1;
        *(uint4*)&Bs[sr * 40 + sk] = b0;
        *(uint4*)&Bs[(64 + sr) * 40 + sk] = b1;
        __syncthreads();
        int kn = k0 + 32;
        if (kn < K) {
            a0 = *(const uint4*)(Ag0 + kn);
            a1 = *(const uint4*)(Ag1 + kn);
            b0 = *(const uint4*)(Bg0 + kn);
            b1 = *(const uint4*)(Bg1 + kn);
        }
        bf16x8 af[4], bfr[4];
        #pragma unroll
        for (int i = 0; i < 4; i++) {
            af[i]  = *(const bf16x8*)&As[(wr * 64 + i * 16 + lr) * 40 + quad * 8];
            bfr[i] = *(const bf16x8*)&Bs[(wc * 64 + i * 16 + lr) * 40 + quad * 8];
        }
        #pragma unroll
        for (int mi = 0; mi < 4; mi++)
            #pragma unroll
            for (int ni = 0; ni < 4; ni++)
                acc[mi][ni] = __builtin_amdgcn_mfma_f32_16x16x32_bf16(af[mi], bfr[ni], acc[mi][ni], 0, 0, 0);
    }
    #pragma unroll
    for (int mi = 0; mi < 4; mi++)
        #pragma unroll
        for (int ni = 0; ni < 4; ni++) {
            int col = colBase + wc * 64 + ni * 16 + lr;
            if (col < N) {
                float bv = bias[col];
                #pragma unroll
                for (int r = 0; r < 4; r++) {
                    int row = rowBase + wr * 64 + mi * 16 + quad * 4 + r;
                    C[(size_t)row * N + col] = acc[mi][ni][r] + bv;
                }
            }
        }
}

// ---------------- h0 recurrence + gates (fp32 exact, one WG per batch row) ----------------
__global__ __launch_bounds__(128) void h0_chain(const float* __restrict__ Xa,   // (T*B) x 128
                                                const float* __restrict__ Wah,  // 128 x 128
                                                const float* __restrict__ Wa,   // 128 x 2
                                                const float* __restrict__ ba,   // 2
                                                float2* __restrict__ ns) {      // T*B
    int b = blockIdx.x;      // batch 0..63
    int j = threadIdx.x;     // 0..127
    __shared__ float WahS[HADIM * HADIM];
    __shared__ float h0s[HADIM];
    __shared__ float red[4];
    for (int i = j; i < HADIM * HADIM; i += 128) WahS[i] = Wah[i];
    h0s[j] = 0.f;
    float wa0 = Wa[j * 2 + 0], wa1 = Wa[j * 2 + 1];
    float ba0 = ba[0], ba1 = ba[1];
    __syncthreads();
    for (int t = 0; t < TSTEPS; t++) {
        float acc = Xa[((size_t)t * BATCH + b) * HADIM + j];
        for (int k = 0; k < HADIM; k++) acc += h0s[k] * WahS[k * HADIM + j];
        float h0n = tanhf(acc);
        float p0 = h0n * wa0, p1 = h0n * wa1;
        for (int off = 32; off > 0; off >>= 1) {
            p0 += __shfl_down(p0, off);
            p1 += __shfl_down(p1, off);
        }
        int wv = j >> 6;
        if ((j & 63) == 0) { red[wv * 2 + 0] = p0; red[wv * 2 + 1] = p1; }
        __syncthreads();
        float n = 1.f / (1.f + __expf(-(red[0] + red[2] + ba0)));
        float s = 1.f / (1.f + __expf(-(red[1] + red[3] + ba1)));
        if (j == 0) ns[t * BATCH + b] = make_float2(n, s);
        h0s[j] = h0n;
        __syncthreads();
    }
}

// ---------------- persistent h1 recurrence: all 128 steps, one launch ----------------
// 64 WGs x 256 threads. WG w owns output columns [w*16, w*16+16) with its Whh^T
// slice resident in LDS. Per step: read full h1 (hs[t-1]) as A-fragments from
// global, MFMA, gate, write slice of hs[t], then cross a device-scope grid
// barrier (one counter slot per step; all 64 WGs are co-resident).
__global__ __launch_bounds__(256) void rnn_persist(const unsigned short* __restrict__ WhhT,
                                                   const float* __restrict__ Xi,
                                                   const float2* __restrict__ ns,
                                                   unsigned short* __restrict__ hs,
                                                   float* __restrict__ h1f,
                                                   unsigned int* __restrict__ bar) {
    __shared__ unsigned short Bsl[16 * 1032];   // 16 cols x 1024 K, +8 pad (2-way conflicts only)
    const int w = blockIdx.x;          // column group 0..63
    const int tid = threadIdx.x;
    const int wave = tid >> 6, lane = tid & 63;
    const int quad = lane >> 4, lr = lane & 15;
    // stage Whh^T slice: rows w*16 .. w*16+16 (each row = 1024 contiguous bf16)
    for (int i = tid; i < 16 * 128; i += 256) {
        int r = i >> 7, k = (i & 127) * 8;
        *(uint4*)&Bsl[r * 1032 + k] = *(const uint4*)&WhhT[(size_t)(w * 16 + r) * HDIM + k];
    }
    __syncthreads();
    const int col = w * 16 + lr;       // this lane's output column
    const int mrow = wave * 16 + lr;   // this lane's A row (batch)
    for (int t = 0; t < TSTEPS; t++) {
        const float* Xit = Xi + (size_t)t * BATCH * HDIM;
        // prefetch epilogue operands so the MFMA loop hides their latency
        float xi[4]; float2 g[4];
        #pragma unroll
        for (int r = 0; r < 4; r++) {
            int brow = wave * 16 + quad * 4 + r;
            xi[r] = Xit[(size_t)brow * HDIM + col];
            g[r] = ns[t * BATCH + brow];
        }
        f32x4 acc = {};
        if (t > 0) {
            const unsigned short* Ap = hs + (size_t)(t - 1) * BATCH * HDIM
                                          + (size_t)mrow * HDIM + quad * 8;
            const unsigned short* Bp = (const unsigned short*)Bsl + lr * 1032 + quad * 8;
            #pragma unroll 8
            for (int k0 = 0; k0 < HDIM; k0 += 32) {
                bf16x8 av = *(const bf16x8*)(Ap + k0);
                bf16x8 bv = *(const bf16x8*)(Bp + k0);
                acc = __builtin_amdgcn_mfma_f32_16x16x32_bf16(av, bv, acc, 0, 0, 0);
            }
        }
        unsigned short* hst = hs + (size_t)t * BATCH * HDIM;
        #pragma unroll
        for (int r = 0; r < 4; r++) {
            int brow = wave * 16 + quad * 4 + r;
            float pre = acc[r] + xi[r];
            float z = g[r].x * pre;
            float th = tanhf(z);
            float sg = 1.f / (1.f + __expf(-z));
            float h1n = (1.f - g[r].y) * th + g[r].y * sg;
            hst[(size_t)brow * HDIM + col] = f2bf(h1n);
            if (t == TSTEPS - 1) h1f[(size_t)brow * HDIM + col] = h1n;
        }
        if (t < TSTEPS - 1) {
            __threadfence();               // release: make hs[t] stores device-visible
            __syncthreads();
            if (tid == 0) {
                __hip_atomic_fetch_add(&bar[t], 1u, __ATOMIC_RELEASE, __HIP_MEMORY_SCOPE_AGENT);
                while (__hip_atomic_load(&bar[t], __ATOMIC_RELAXED, __HIP_MEMORY_SCOPE_AGENT) < 64u)
                    __builtin_amdgcn_s_sleep(1);
            }
            __syncthreads();
            __threadfence();               // acquire: invalidate stale cached h1
        }
    }
}

extern "C" void kernel_launch(void* const* d_in, const int* in_sizes, int n_in,
                              void* d_out, int out_size, void* d_ws, size_t ws_size,
                              hipStream_t stream) {
    const int*   tokens = (const int*)d_in[0];
    const float* emb    = (const float*)d_in[1];
    const float* Wax    = (const float*)d_in[2];
    const float* Wah    = (const float*)d_in[3];
    const float* bah    = (const float*)d_in[4];
    const float* Wa     = (const float*)d_in[5];
    const float* ba     = (const float*)d_in[6];
    const float* Wih    = (const float*)d_in[7];
    const float* Whh    = (const float*)d_in[8];
    const float* bh     = (const float*)d_in[9];
    const float* Wd     = (const float*)d_in[10];
    const float* bd     = (const float*)d_in[11];
    float* out = (float*)d_out;

    char* ws = (char*)d_ws;
    size_t off = 0;
    auto alloc = [&](size_t bytes) -> void* {
        void* p = ws + off;
        off += (bytes + 255) & ~(size_t)255;
        return p;
    };
    unsigned short* WihT = (unsigned short*)alloc((size_t)HDIM * DDIM * 2);      // 2 MB
    unsigned short* WaxT = (unsigned short*)alloc((size_t)HADIM * DDIM * 2);     // 256 KB
    unsigned short* WhhT = (unsigned short*)alloc((size_t)HDIM * HDIM * 2);      // 2 MB
    unsigned short* WdT  = (unsigned short*)alloc((size_t)VOCAB * HDIM * 2);     // ~20 MB
    unsigned short* xb   = (unsigned short*)alloc((size_t)MROWS * DDIM * 2);     // 16 MB
    float*          Xi   = (float*)alloc((size_t)MROWS * HDIM * 4);              // 32 MB
    float*          Xa   = (float*)alloc((size_t)MROWS * HADIM * 4);             // 4 MB
    unsigned short* hs   = (unsigned short*)alloc((size_t)MROWS * HDIM * 2);     // 16 MB
    float2*         ns   = (float2*)alloc((size_t)TSTEPS * BATCH * 8);           // 64 KB
    unsigned int*   bar  = (unsigned int*)alloc((size_t)TSTEPS * 4);             // 512 B

    // 1. weight transposes (fp32 -> bf16, B^T layout)
    transpose_cast<<<dim3(32, 32), 256, 0, stream>>>(Wih, WihT, DDIM, HDIM);
    transpose_cast<<<dim3(4, 32), 256, 0, stream>>>(Wax, WaxT, DDIM, HADIM);
    transpose_cast<<<dim3(32, 32), 256, 0, stream>>>(Whh, WhhT, HDIM, HDIM);
    transpose_cast<<<dim3(313, 32), 256, 0, stream>>>(Wd, WdT, HDIM, VOCAB);
    // 2. gather x = emb[tokens] -> bf16 ; zero barrier counters
    gather_cast<<<MROWS, 256, 0, stream>>>(tokens, emb, xb);
    zero_u32<<<1, 256, 0, stream>>>(bar, TSTEPS);
    // 3. Xa = x @ Wax + bah ; h0 chain + gates ; Xi = x @ Wih + bh
    gemm128<<<dim3(MROWS / 128, 1), 256, 0, stream>>>(xb, WaxT, bah, Xa, MROWS, HADIM, DDIM);
    h0_chain<<<BATCH, 128, 0, stream>>>(Xa, Wah, Wa, ba, ns);
    gemm128<<<dim3(MROWS / 128, HDIM / 128), 256, 0, stream>>>(xb, WihT, bh, Xi, MROWS, HDIM, DDIM);
    // 4. h1 recurrence: single persistent launch, grid barrier per step
    rnn_persist<<<64, 256, 0, stream>>>(WhhT, Xi, ns, hs, out + (size_t)MROWS * VOCAB, bar);
    // 5. decoded = hs @ Wd + bd
    gemm128<<<dim3(MROWS / 128, (VOCAB + 127) / 128), 256, 0, stream>>>(hs, WdT, bd, out, MROWS, VOCAB, HDIM);
}